// Round 3
// baseline (539.309 us; speedup 1.0000x reference)
//
#include <hip/hip_runtime.h>
#include <stdint.h>

// ---------------- problem constants ----------------
#define E_DIM 1024
#define M_DIM 256
#define B_DIM 4
#define S_DIM 2048
#define NTOK  8192      // B*S
#define CHUNK 64
#define NCHUNK 32       // S / CHUNK
#define NCB   128       // B * NCHUNK

typedef unsigned short u16;
typedef unsigned int   u32;
typedef __attribute__((ext_vector_type(8))) short short8;
typedef __attribute__((ext_vector_type(4))) float floatx4;

// ---------------- workspace layout (bytes) ----------------
#define OFF_WKQV   ((size_t)0)            // 768*1024 bf16 = 1,572,864
#define OFF_WOUT   ((size_t)1572864)      // 1024*256 bf16 = 524,288
#define OFF_WF1    ((size_t)2097152)      // 4096*1024 bf16 = 8,388,608
#define OFF_WF2    ((size_t)10485760)     // 8,388,608
#define OFF_BKQV   ((size_t)18874368)     // 768 f32
#define OFF_BETA   ((size_t)18877440)     // 8192 f32
#define OFF_DECAY  ((size_t)18910208)     // 8192 f32
#define OFF_P      ((size_t)18942976)     // 128*65 f32
#define OFF_WW     ((size_t)18976256)     // 128*64 f32
#define OFF_ABUF   ((size_t)19009024)     // 128*64*64 f32 = 2,097,152
#define OFF_XN     ((size_t)21106176)     // 8192*1024 bf16 = 16,777,216  [h aliases]
#define OFF_KQV    ((size_t)37883392)     // 8192*768 f32 = 25,165,824
#define OFF_T      ((size_t)63049216)     // 128*65536 f32 = 33,554,432   [y1 aliases]
#define OFF_STATES ((size_t)96603648)     // 128*65536 f32 = 33,554,432   [g starts here]
#define OFF_RO     ((size_t)130158080)    // 8192*256 bf16 = 4,194,304
#define OFF_H      OFF_XN                 // 8192*1024 bf16 (xn dead after kqv gemm)
#define OFF_Y1     OFF_T                  // 8192*1024 f32 (T dead after mem_scan)
#define OFF_G      OFF_STATES             // 8192*4096 bf16 = 67,108,864 (states+ro dead)

// ---------------- helpers ----------------
__device__ __forceinline__ u16 f2bf(float f) {
    union { float f; u32 u; } a; a.f = f;
    u32 u = a.u;
    return (u16)((u + 0x7fffu + ((u >> 16) & 1u)) >> 16);
}
__device__ __forceinline__ u32 pack2bf(float a, float b) {
    return (u32)f2bf(a) | ((u32)f2bf(b) << 16);
}
__device__ __forceinline__ float sigmoidf_(float x) { return 1.0f / (1.0f + expf(-x)); }

// async global->LDS, 16 bytes per lane; LDS dest contiguous in lane order.
__device__ __forceinline__ void gload_lds16(const u16* g, u16* l) {
    __builtin_amdgcn_global_load_lds((const __attribute__((address_space(1))) void*)g,
                                     (__attribute__((address_space(3))) void*)l, 16, 0, 0);
}

// two-value block reduction across 256 threads (4 waves)
__device__ __forceinline__ void block_reduce_2(float& a, float& b, float* red, int t) {
#pragma unroll
    for (int o = 32; o > 0; o >>= 1) { a += __shfl_xor(a, o); b += __shfl_xor(b, o); }
    if ((t & 63) == 0) { red[t >> 6] = a; red[4 + (t >> 6)] = b; }
    __syncthreads();
    a = red[0] + red[1] + red[2] + red[3];
    b = red[4] + red[5] + red[6] + red[7];
    __syncthreads();
}

// ---------------- weight convert / pack ----------------
__global__ void f2bf4_kernel(const float4* __restrict__ in, uint2* __restrict__ out, int n4) {
    int i = blockIdx.x * 256 + threadIdx.x;
    if (i < n4) {
        float4 v = in[i];
        uint2 o; o.x = pack2bf(v.x, v.y); o.y = pack2bf(v.z, v.w);
        out[i] = o;
    }
}
__global__ void pack_kqv_w(const float4* __restrict__ wk, const float4* __restrict__ wq,
                           const float4* __restrict__ wv, uint2* __restrict__ out) {
    int i = blockIdx.x * 256 + threadIdx.x;      // < 196608 (float4 units)
    int sec = i >> 16;
    int off = i & 65535;
    const float4* src = (sec == 0) ? wk : ((sec == 1) ? wq : wv);
    float4 v = src[off];
    uint2 o; o.x = pack2bf(v.x, v.y); o.y = pack2bf(v.z, v.w);
    out[i] = o;
}
__global__ void pack_bias(const float* __restrict__ bk, const float* __restrict__ bq,
                          const float* __restrict__ bv, float* __restrict__ out) {
    int i = blockIdx.x * 256 + threadIdx.x;      // < 768
    if (i < 256) out[i] = bk[i];
    else if (i < 512) out[i] = bq[i - 256];
    else out[i] = bv[i - 512];
}

// ---------------- LN kernels ----------------
__global__ __launch_bounds__(256) void ln1_gates(
    const float* __restrict__ x, const float* __restrict__ g, const float* __restrict__ b,
    const float* __restrict__ wgw, const float* __restrict__ bgw,
    const float* __restrict__ wgf, const float* __restrict__ bgf,
    u16* __restrict__ xn, float* __restrict__ beta, float* __restrict__ decay)
{
    __shared__ float red[8];
    const int row = blockIdx.x;
    const int t = threadIdx.x;
    const float4 v = ((const float4*)(x + (size_t)row * E_DIM))[t];
    float s  = v.x + v.y + v.z + v.w;
    float ss = v.x * v.x + v.y * v.y + v.z * v.z + v.w * v.w;
    block_reduce_2(s, ss, red, t);
    const float mean = s * (1.0f / E_DIM);
    const float var  = ss * (1.0f / E_DIM) - mean * mean;
    const float rstd = rsqrtf(var + 1e-5f);
    const float4 gg = ((const float4*)g)[t];
    const float4 bb = ((const float4*)b)[t];
    float4 xnv;
    xnv.x = (v.x - mean) * rstd * gg.x + bb.x;
    xnv.y = (v.y - mean) * rstd * gg.y + bb.y;
    xnv.z = (v.z - mean) * rstd * gg.z + bb.z;
    xnv.w = (v.w - mean) * rstd * gg.w + bb.w;
    uint2 o; o.x = pack2bf(xnv.x, xnv.y); o.y = pack2bf(xnv.z, xnv.w);
    ((uint2*)(xn + (size_t)row * E_DIM))[t] = o;
    const float4 w1 = ((const float4*)wgw)[t];
    const float4 w2 = ((const float4*)wgf)[t];
    float dg = xnv.x * w1.x + xnv.y * w1.y + xnv.z * w1.z + xnv.w * w1.w;
    float df = xnv.x * w2.x + xnv.y * w2.y + xnv.z * w2.z + xnv.w * w2.w;
    block_reduce_2(dg, df, red, t);
    if (t == 0) {
        beta[row]  = sigmoidf_(dg + bgw[0]);
        decay[row] = sigmoidf_(df + bgf[0]);
    }
}

__global__ __launch_bounds__(256) void ln2_kernel(
    const float* __restrict__ y1, const float* __restrict__ g, const float* __restrict__ b,
    u16* __restrict__ h)
{
    __shared__ float red[8];
    const int row = blockIdx.x;
    const int t = threadIdx.x;
    const float4 v = ((const float4*)(y1 + (size_t)row * E_DIM))[t];
    float s  = v.x + v.y + v.z + v.w;
    float ss = v.x * v.x + v.y * v.y + v.z * v.z + v.w * v.w;
    block_reduce_2(s, ss, red, t);
    const float mean = s * (1.0f / E_DIM);
    const float var  = ss * (1.0f / E_DIM) - mean * mean;
    const float rstd = rsqrtf(var + 1e-5f);
    const float4 gg = ((const float4*)g)[t];
    const float4 bb = ((const float4*)b)[t];
    float4 xnv;
    xnv.x = (v.x - mean) * rstd * gg.x + bb.x;
    xnv.y = (v.y - mean) * rstd * gg.y + bb.y;
    xnv.z = (v.z - mean) * rstd * gg.z + bb.z;
    xnv.w = (v.w - mean) * rstd * gg.w + bb.w;
    uint2 o; o.x = pack2bf(xnv.x, xnv.y); o.y = pack2bf(xnv.z, xnv.w);
    ((uint2*)(h + (size_t)row * E_DIM))[t] = o;
}

// ---------------- k/q/v activation ----------------
__global__ __launch_bounds__(256) void kqv_act(float* __restrict__ kqv) {
    __shared__ float red[8];
    const int row = blockIdx.x;
    const int t = threadIdx.x;
    float* p = kqv + (size_t)row * 768;
    float kv = p[t], qv = p[256 + t], vv = p[512 + t];
    float sk = kv * kv, sq = qv * qv;
    block_reduce_2(sk, sq, red, t);
    float nk = fmaxf(sqrtf(sk), 1e-12f);
    float nq = fmaxf(sqrtf(sq), 1e-12f);
    p[t]       = kv / nk;
    p[256 + t] = qv / nq;
    p[512 + t] = tanhf(vv);
}

// ---------------- chunk prep ----------------
__global__ void chunk_prep(const float* __restrict__ beta, const float* __restrict__ decay,
                           float* __restrict__ P, float* __restrict__ ww) {
    int cb = blockIdx.x;
    int b = cb >> 5, c = cb & 31;
    int tb = b * S_DIM + c * CHUNK;
    int j = threadIdx.x;
    __shared__ float d[64], bt[64], Ps[65];
    d[j]  = decay[tb + j];
    bt[j] = beta[tb + j];
    __syncthreads();
    if (j == 0) {
        float p = 1.0f; Ps[0] = 1.0f;
        for (int i = 0; i < 64; i++) { p *= d[i]; Ps[i + 1] = p; }
    }
    __syncthreads();
    P[cb * 65 + j] = Ps[j];
    if (j == 0) P[cb * 65 + 64] = Ps[64];
    ww[cb * 64 + j] = bt[j] / Ps[j + 1];
}

// ---------------- per-chunk state increment ----------------
__global__ __launch_bounds__(256) void t_kernel(const float* __restrict__ kqv,
                                                const float* __restrict__ P,
                                                const float* __restrict__ ww,
                                                float* __restrict__ T) {
    int cb = blockIdx.y;
    int tile = blockIdx.x;
    int r0 = (tile >> 2) * 64, c0 = (tile & 3) * 64;
    int b = cb >> 5, c = cb & 31;
    int tb = b * S_DIM + c * CHUNK;
    float p64 = P[cb * 65 + 64];
    __shared__ float Vs[64][65], Ks[64][65];
    int t = threadIdx.x;
#pragma unroll
    for (int i = 0; i < 16; i++) {
        int idx = t + i * 256; int j = idx >> 6, col = idx & 63;
        float sc = ww[cb * 64 + j] * p64;
        Vs[j][col] = kqv[(size_t)(tb + j) * 768 + 512 + r0 + col] * sc;
        Ks[j][col] = kqv[(size_t)(tb + j) * 768 + 0   + c0 + col];
    }
    __syncthreads();
    int tr = t >> 4, tc = t & 15;
    float a[4][4] = {};
    for (int j = 0; j < 64; j++) {
        float vv[4], kk[4];
#pragma unroll
        for (int r = 0; r < 4; r++)  vv[r] = Vs[j][tr * 4 + r];
#pragma unroll
        for (int cc = 0; cc < 4; cc++) kk[cc] = Ks[j][tc * 4 + cc];
#pragma unroll
        for (int r = 0; r < 4; r++)
#pragma unroll
            for (int cc = 0; cc < 4; cc++) a[r][cc] += vv[r] * kk[cc];
    }
#pragma unroll
    for (int r = 0; r < 4; r++)
#pragma unroll
        for (int cc = 0; cc < 4; cc++)
            T[(size_t)cb * 65536 + (size_t)(r0 + tr * 4 + r) * 256 + (c0 + tc * 4 + cc)] = a[r][cc];
}

// ---------------- element-parallel chunk scan ----------------
__global__ void mem_scan(const float* __restrict__ mem0, const float* __restrict__ T,
                         const float* __restrict__ P, float* __restrict__ states,
                         float* __restrict__ memOut) {
    int gid = blockIdx.x * 256 + threadIdx.x;
    int b = gid >> 16; int e = gid & 65535;
    float s = mem0[gid];
    for (int c = 0; c < NCHUNK; c++) {
        int cb = b * NCHUNK + c;
        states[(size_t)cb * 65536 + e] = s;
        s = P[cb * 65 + 64] * s + T[(size_t)cb * 65536 + e];
    }
    memOut[gid] = s;
}

// ---------------- intra-chunk attention matrix ----------------
__global__ __launch_bounds__(256) void qk_attn(const float* __restrict__ kqv,
                                               const float* __restrict__ P,
                                               const float* __restrict__ ww,
                                               float* __restrict__ Abuf) {
    int cb = blockIdx.x;
    int b = cb >> 5, c = cb & 31;
    int tb = b * S_DIM + c * CHUNK;
    __shared__ float Qs[64][65], Ks[64][65];
    int t = threadIdx.x;
    int tr = t >> 4, tc = t & 15;
    float acc[4][4] = {};
    for (int kt = 0; kt < 4; kt++) {
        __syncthreads();
#pragma unroll
        for (int i = 0; i < 16; i++) {
            int idx = t + i * 256; int rr = idx >> 6, cc2 = idx & 63;
            Qs[rr][cc2] = kqv[(size_t)(tb + rr) * 768 + 256 + kt * 64 + cc2];
            Ks[rr][cc2] = kqv[(size_t)(tb + rr) * 768 + 0   + kt * 64 + cc2];
        }
        __syncthreads();
        for (int kk = 0; kk < 64; kk++) {
            float qq[4], kx[4];
#pragma unroll
            for (int r = 0; r < 4; r++)  qq[r] = Qs[tr * 4 + r][kk];
#pragma unroll
            for (int cc = 0; cc < 4; cc++) kx[cc] = Ks[tc * 4 + cc][kk];
#pragma unroll
            for (int r = 0; r < 4; r++)
#pragma unroll
                for (int cc = 0; cc < 4; cc++) acc[r][cc] += qq[r] * kx[cc];
        }
    }
#pragma unroll
    for (int r = 0; r < 4; r++) {
#pragma unroll
        for (int cc = 0; cc < 4; cc++) {
            int i = tr * 4 + r, j = tc * 4 + cc;
            float v = (j < i) ? acc[r][cc] * (P[cb * 65 + i] * ww[cb * 64 + j]) : 0.0f;
            Abuf[(size_t)cb * 4096 + i * 64 + j] = v;
        }
    }
}

// ---------------- readout ----------------
__global__ __launch_bounds__(256) void readout_k(const float* __restrict__ kqv,
                                                 const float* __restrict__ Abuf,
                                                 const float* __restrict__ states,
                                                 const float* __restrict__ P,
                                                 u16* __restrict__ ro) {
    int cb = blockIdx.y;
    int rt = blockIdx.x;
    int b = cb >> 5, c = cb & 31;
    int tb = b * S_DIM + c * CHUNK;
    int r0 = rt * 64;
    __shared__ float As[64][65], Vs[64][65], Qs[64][65], Ms[64][65];
    int t = threadIdx.x;
    int tr = t >> 4, tc = t & 15;
#pragma unroll
    for (int i = 0; i < 16; i++) {
        int idx = t + i * 256; int rr = idx >> 6, cc2 = idx & 63;
        As[rr][cc2] = Abuf[(size_t)cb * 4096 + rr * 64 + cc2];
        Vs[rr][cc2] = kqv[(size_t)(tb + rr) * 768 + 512 + r0 + cc2];
    }
    __syncthreads();
    float acc[4][4] = {};
    for (int j = 0; j < 64; j++) {
        float aa[4], vv[4];
#pragma unroll
        for (int r = 0; r < 4; r++)  aa[r] = As[tr * 4 + r][j];
#pragma unroll
        for (int cc = 0; cc < 4; cc++) vv[cc] = Vs[j][tc * 4 + cc];
#pragma unroll
        for (int r = 0; r < 4; r++)
#pragma unroll
            for (int cc = 0; cc < 4; cc++) acc[r][cc] += aa[r] * vv[cc];
    }
    float acc2[4][4] = {};
    for (int kt = 0; kt < 4; kt++) {
        __syncthreads();
#pragma unroll
        for (int i = 0; i < 16; i++) {
            int idx = t + i * 256; int rr = idx >> 6, cc2 = idx & 63;
            Qs[rr][cc2] = kqv[(size_t)(tb + rr) * 768 + 256 + kt * 64 + cc2];
            Ms[rr][cc2] = states[(size_t)cb * 65536 + (size_t)(r0 + rr) * 256 + kt * 64 + cc2];
        }
        __syncthreads();
        for (int kk = 0; kk < 64; kk++) {
            float qq[4], mm[4];
#pragma unroll
            for (int r = 0; r < 4; r++)  qq[r] = Qs[tr * 4 + r][kk];
#pragma unroll
            for (int cc = 0; cc < 4; cc++) mm[cc] = Ms[tc * 4 + cc][kk];
#pragma unroll
            for (int r = 0; r < 4; r++)
#pragma unroll
                for (int cc = 0; cc < 4; cc++) acc2[r][cc] += qq[r] * mm[cc];
        }
    }
#pragma unroll
    for (int r = 0; r < 4; r++) {
#pragma unroll
        for (int cc = 0; cc < 4; cc++) {
            int i = tr * 4 + r;
            float val = acc[r][cc] + P[cb * 65 + i] * acc2[r][cc];
            ro[(size_t)(tb + i) * 256 + r0 + tc * 4 + cc] = f2bf(val);
        }
    }
}

// ---------------- bf16 MFMA GEMM: C[M,N] = A[M,K] @ B[N,K]^T (+epilogue) ----------------
// 64x128 tile, BK=32, 256 threads (4 waves as 2Mx2N, each 32x64), 16x16x32 MFMA.
// Double-buffered LDS + global_load_lds(16B): ONE barrier per K-iter; loads for
// tile k+1 are issued right after the barrier and fly during tile k's MFMA, so
// the next barrier's vmcnt(0) drain is cheap. WAR-safe: buf[(k+1)&1]'s last
// ds_reads were drained by the current barrier's lgkmcnt(0).
#define EPI_BIAS  0
#define EPI_RESID 1
#define EPI_GELU  2

template<int EPI>
__global__ __launch_bounds__(256) void gemm_bt(
    const u16* __restrict__ A, int lda,
    const u16* __restrict__ B, int ldb,
    const float* __restrict__ bias,
    const float* __restrict__ resid,
    float* __restrict__ outF, u16* __restrict__ outB,
    int ldc, int K)
{
    __shared__ u16 As[2][64 * 32];
    __shared__ u16 Bs[2][128 * 32];
    const int t = threadIdx.x;
    const int lane = t & 63;
    const int w = t >> 6;
    const int waveM = (w >> 1) * 32;
    const int waveN = (w & 1) * 64;
    const int m0 = blockIdx.y * 64;
    const int n0 = blockIdx.x * 128;

    // staging addressing: chunk idx -> row = idx>>2, colchunk = (idx&3)*8
    const int sr = t >> 2, sc = (t & 3) * 8;
    const u16* Ag  = A + (size_t)(m0 + sr) * lda + sc;
    const u16* Bg0 = B + (size_t)(n0 + sr) * ldb + sc;
    const u16* Bg1 = B + (size_t)(n0 + 64 + sr) * ldb + sc;

    floatx4 acc[2][4] = {};

    const int kg = (lane >> 4) * 8;
    const int rsel = lane & 15;
    const int NK = K >> 5;

    // prologue: stage tile 0 into buffer 0
    gload_lds16(Ag, As[0] + t * 8);
    gload_lds16(Bg0, Bs[0] + t * 8);
    gload_lds16(Bg1, Bs[0] + (t + 256) * 8);

    for (int kt = 0; kt < NK; kt++) {
        __syncthreads();                    // drains buf[kt&1] loads (vmcnt) + prev ds_reads (lgkm)
        const int cur = kt & 1;
        if (kt + 1 < NK) {
            const int kof = (kt + 1) * 32;
            gload_lds16(Ag + kof, As[cur ^ 1] + t * 8);
            gload_lds16(Bg0 + kof, Bs[cur ^ 1] + t * 8);
            gload_lds16(Bg1 + kof, Bs[cur ^ 1] + (t + 256) * 8);
        }
        short8 af[2], bfr[4];
#pragma unroll
        for (int i = 0; i < 2; i++)
            af[i] = *(const short8*)(As[cur] + (waveM + i * 16 + rsel) * 32 + kg);
#pragma unroll
        for (int j = 0; j < 4; j++)
            bfr[j] = *(const short8*)(Bs[cur] + (waveN + j * 16 + rsel) * 32 + kg);
#pragma unroll
        for (int i = 0; i < 2; i++)
#pragma unroll
            for (int j = 0; j < 4; j++)
                acc[i][j] = __builtin_amdgcn_mfma_f32_16x16x32_bf16(af[i], bfr[j], acc[i][j], 0, 0, 0);
    }

    const int rbase = (lane >> 4) * 4;
#pragma unroll
    for (int i = 0; i < 2; i++) {
#pragma unroll
        for (int j = 0; j < 4; j++) {
            const int col = n0 + waveN + j * 16 + rsel;
            const float bv = bias[col];
#pragma unroll
            for (int r = 0; r < 4; r++) {
                const int row = m0 + waveM + i * 16 + rbase + r;
                const size_t oidx = (size_t)row * ldc + col;
                float v = acc[i][j][r] + bv;
                if (EPI == EPI_BIAS) {
                    outF[oidx] = v;
                } else if (EPI == EPI_RESID) {
                    outF[oidx] = v + resid[oidx];
                } else {
                    float gl = 0.5f * v * (1.0f + erff(v * 0.70710678118654752f));
                    outB[oidx] = f2bf(gl);
                }
            }
        }
    }
}

// ---------------- launch ----------------
extern "C" void kernel_launch(void* const* d_in, const int* in_sizes, int n_in,
                              void* d_out, int out_size, void* d_ws, size_t ws_size,
                              hipStream_t stream) {
    const float* x     = (const float*)d_in[0];
    const float* mem0  = (const float*)d_in[1];
    const float* w_k   = (const float*)d_in[2];
    const float* b_k   = (const float*)d_in[3];
    const float* w_q   = (const float*)d_in[4];
    const float* b_q   = (const float*)d_in[5];
    const float* w_v   = (const float*)d_in[6];
    const float* b_v   = (const float*)d_in[7];
    const float* w_out = (const float*)d_in[8];
    const float* b_out = (const float*)d_in[9];
    const float* w_gw  = (const float*)d_in[10];
    const float* b_gw  = (const float*)d_in[11];
    const float* w_gf  = (const float*)d_in[12];
    const float* b_gf  = (const float*)d_in[13];
    const float* ln1g  = (const float*)d_in[14];
    const float* ln1b  = (const float*)d_in[15];
    const float* ln2g  = (const float*)d_in[16];
    const float* ln2b  = (const float*)d_in[17];
    const float* w_f1  = (const float*)d_in[18];
    const float* b_f1  = (const float*)d_in[19];
    const float* w_f2  = (const float*)d_in[20];
    const float* b_f2  = (const float*)d_in[21];

    char* ws = (char*)d_ws;
    u16*   wkqv  = (u16*)(ws + OFF_WKQV);
    u16*   wout  = (u16*)(ws + OFF_WOUT);
    u16*   wf1   = (u16*)(ws + OFF_WF1);
    u16*   wf2   = (u16*)(ws + OFF_WF2);
    float* bkqv  = (float*)(ws + OFF_BKQV);
    float* beta  = (float*)(ws + OFF_BETA);
    float* decay = (float*)(ws + OFF_DECAY);
    float* P     = (float*)(ws + OFF_P);
    float* ww    = (float*)(ws + OFF_WW);
    float* Abuf  = (float*)(ws + OFF_ABUF);
    u16*   xn    = (u16*)(ws + OFF_XN);
    float* kqv   = (float*)(ws + OFF_KQV);
    float* T     = (float*)(ws + OFF_T);
    float* states= (float*)(ws + OFF_STATES);
    u16*   ro    = (u16*)(ws + OFF_RO);
    u16*   h     = (u16*)(ws + OFF_H);
    float* y1    = (float*)(ws + OFF_Y1);
    u16*   g     = (u16*)(ws + OFF_G);

    float* out_x   = (float*)d_out;
    float* out_mem = out_x + (size_t)NTOK * E_DIM;

    // weight conversion (runs every call: inputs restored each launch)
    pack_kqv_w<<<768, 256, 0, stream>>>((const float4*)w_k, (const float4*)w_q,
                                        (const float4*)w_v, (uint2*)wkqv);
    f2bf4_kernel<<<256, 256, 0, stream>>>((const float4*)w_out, (uint2*)wout, 1024 * 256 / 4);
    f2bf4_kernel<<<4096, 256, 0, stream>>>((const float4*)w_f1, (uint2*)wf1, 4096 * 1024 / 4);
    f2bf4_kernel<<<4096, 256, 0, stream>>>((const float4*)w_f2, (uint2*)wf2, 1024 * 4096 / 4);
    pack_bias<<<3, 256, 0, stream>>>(b_k, b_q, b_v, bkqv);

    // LN1 + gate scalars
    ln1_gates<<<NTOK, 256, 0, stream>>>(x, ln1g, ln1b, w_gw, b_gw, w_gf, b_gf, xn, beta, decay);

    // k/q/v projections: [8192,768] = xn @ wkqv^T
    gemm_bt<EPI_BIAS><<<dim3(6, 128), 256, 0, stream>>>(xn, 1024, wkqv, 1024, bkqv, nullptr,
                                                        kqv, nullptr, 768, 1024);
    kqv_act<<<NTOK, 256, 0, stream>>>(kqv);

    // chunked linear-attention scan
    chunk_prep<<<NCB, 64, 0, stream>>>(beta, decay, P, ww);
    t_kernel<<<dim3(16, NCB), 256, 0, stream>>>(kqv, P, ww, T);
    mem_scan<<<1024, 256, 0, stream>>>(mem0, T, P, states, out_mem);
    qk_attn<<<NCB, 256, 0, stream>>>(kqv, P, ww, Abuf);
    readout_k<<<dim3(4, NCB), 256, 0, stream>>>(kqv, Abuf, states, P, ro);

    // mixer + residual
    gemm_bt<EPI_RESID><<<dim3(8, 128), 256, 0, stream>>>(ro, 256, wout, 256, b_out, x,
                                                         y1, nullptr, 1024, 256);
    // LN2 + FFN
    ln2_kernel<<<NTOK, 256, 0, stream>>>(y1, ln2g, ln2b, h);
    gemm_bt<EPI_GELU><<<dim3(32, 128), 256, 0, stream>>>(h, 1024, wf1, 1024, b_f1, nullptr,
                                                         nullptr, g, 4096, 1024);
    gemm_bt<EPI_RESID><<<dim3(8, 128), 256, 0, stream>>>(g, 4096, wf2, 4096, b_f2, y1,
                                                         out_x, nullptr, 1024, 4096);
}

// Round 4
// 531.428 us; speedup vs baseline: 1.0148x; 1.0148x over previous
//
#include <hip/hip_runtime.h>
#include <stdint.h>

// ---------------- problem constants ----------------
#define E_DIM 1024
#define M_DIM 256
#define B_DIM 4
#define S_DIM 2048
#define NTOK  8192      // B*S
#define CHUNK 64
#define NCHUNK 32       // S / CHUNK
#define NCB   128       // B * NCHUNK

typedef unsigned short u16;
typedef unsigned int   u32;
typedef __attribute__((ext_vector_type(8))) short short8;
typedef __attribute__((ext_vector_type(4))) float floatx4;

// ---------------- workspace layout (bytes) ----------------
#define OFF_WKQV   ((size_t)0)            // 768*1024 bf16 = 1,572,864
#define OFF_WOUT   ((size_t)1572864)      // 1024*256 bf16 = 524,288
#define OFF_WF1    ((size_t)2097152)      // 4096*1024 bf16 = 8,388,608
#define OFF_WF2    ((size_t)10485760)     // 8,388,608
#define OFF_BKQV   ((size_t)18874368)     // 768 f32
#define OFF_BETA   ((size_t)18877440)     // 8192 f32
#define OFF_DECAY  ((size_t)18910208)     // 8192 f32
#define OFF_P      ((size_t)18942976)     // 128*65 f32
#define OFF_WW     ((size_t)18976256)     // 128*64 f32
#define OFF_ABUF   ((size_t)19009024)     // 128*64*64 f32 = 2,097,152
#define OFF_XN     ((size_t)21106176)     // 8192*1024 bf16 = 16,777,216  [h aliases]
#define OFF_KQV    ((size_t)37883392)     // 8192*768 f32 = 25,165,824
#define OFF_T      ((size_t)63049216)     // 128*65536 f32 = 33,554,432   [y1 aliases]
#define OFF_STATES ((size_t)96603648)     // 128*65536 f32 = 33,554,432   [g starts here]
#define OFF_RO     ((size_t)130158080)    // 8192*256 bf16 = 4,194,304
#define OFF_H      OFF_XN                 // 8192*1024 bf16 (xn dead after kqv gemm)
#define OFF_Y1     OFF_T                  // 8192*1024 f32 (T dead after mem_scan)
#define OFF_G      OFF_STATES             // 8192*4096 bf16 = 67,108,864 (states+ro dead)

// ---------------- helpers ----------------
__device__ __forceinline__ u16 f2bf(float f) {
    union { float f; u32 u; } a; a.f = f;
    u32 u = a.u;
    return (u16)((u + 0x7fffu + ((u >> 16) & 1u)) >> 16);
}
__device__ __forceinline__ u32 pack2bf(float a, float b) {
    return (u32)f2bf(a) | ((u32)f2bf(b) << 16);
}
__device__ __forceinline__ float sigmoidf_(float x) { return 1.0f / (1.0f + expf(-x)); }

// async global->LDS, 16 bytes per lane; LDS dest contiguous in lane order.
__device__ __forceinline__ void gload_lds16(const u16* g, u16* l) {
    __builtin_amdgcn_global_load_lds((const __attribute__((address_space(1))) void*)g,
                                     (__attribute__((address_space(3))) void*)l, 16, 0, 0);
}

// XOR-swizzle: 16B chunk (row r, kchunk c) lives at LDS slot r*4 + (c ^ ((r>>1)&3)).
// A 16-lane read phase (16 consecutive rows, fixed c) then hits bank-span starts
// {0,4,...,28} each exactly 2x -> 2-way (free, m136). Writes stay lane-contiguous
// (we permute the GLOBAL source per thread, not the LDS destination).
__device__ __forceinline__ int sw_slot(int idx) {            // staging: global kchunk for slot idx
    return ((idx & 3) ^ ((idx >> 3) & 3)) * 8;               // element offset within 32-elem row
}
__device__ __forceinline__ int sw_read(int row, int kc) {    // element offset of frag (row, kchunk kc)
    return row * 32 + ((kc ^ ((row >> 1) & 3)) << 3);
}

// two-value block reduction across 256 threads (4 waves)
__device__ __forceinline__ void block_reduce_2(float& a, float& b, float* red, int t) {
#pragma unroll
    for (int o = 32; o > 0; o >>= 1) { a += __shfl_xor(a, o); b += __shfl_xor(b, o); }
    if ((t & 63) == 0) { red[t >> 6] = a; red[4 + (t >> 6)] = b; }
    __syncthreads();
    a = red[0] + red[1] + red[2] + red[3];
    b = red[4] + red[5] + red[6] + red[7];
    __syncthreads();
}

// ---------------- weight convert / pack ----------------
__global__ void f2bf4_kernel(const float4* __restrict__ in, uint2* __restrict__ out, int n4) {
    int i = blockIdx.x * 256 + threadIdx.x;
    if (i < n4) {
        float4 v = in[i];
        uint2 o; o.x = pack2bf(v.x, v.y); o.y = pack2bf(v.z, v.w);
        out[i] = o;
    }
}
__global__ void pack_kqv_w(const float4* __restrict__ wk, const float4* __restrict__ wq,
                           const float4* __restrict__ wv, uint2* __restrict__ out) {
    int i = blockIdx.x * 256 + threadIdx.x;      // < 196608 (float4 units)
    int sec = i >> 16;
    int off = i & 65535;
    const float4* src = (sec == 0) ? wk : ((sec == 1) ? wq : wv);
    float4 v = src[off];
    uint2 o; o.x = pack2bf(v.x, v.y); o.y = pack2bf(v.z, v.w);
    out[i] = o;
}
__global__ void pack_bias(const float* __restrict__ bk, const float* __restrict__ bq,
                          const float* __restrict__ bv, float* __restrict__ out) {
    int i = blockIdx.x * 256 + threadIdx.x;      // < 768
    if (i < 256) out[i] = bk[i];
    else if (i < 512) out[i] = bq[i - 256];
    else out[i] = bv[i - 512];
}

// ---------------- LN kernels ----------------
__global__ __launch_bounds__(256) void ln1_gates(
    const float* __restrict__ x, const float* __restrict__ g, const float* __restrict__ b,
    const float* __restrict__ wgw, const float* __restrict__ bgw,
    const float* __restrict__ wgf, const float* __restrict__ bgf,
    u16* __restrict__ xn, float* __restrict__ beta, float* __restrict__ decay)
{
    __shared__ float red[8];
    const int row = blockIdx.x;
    const int t = threadIdx.x;
    const float4 v = ((const float4*)(x + (size_t)row * E_DIM))[t];
    float s  = v.x + v.y + v.z + v.w;
    float ss = v.x * v.x + v.y * v.y + v.z * v.z + v.w * v.w;
    block_reduce_2(s, ss, red, t);
    const float mean = s * (1.0f / E_DIM);
    const float var  = ss * (1.0f / E_DIM) - mean * mean;
    const float rstd = rsqrtf(var + 1e-5f);
    const float4 gg = ((const float4*)g)[t];
    const float4 bb = ((const float4*)b)[t];
    float4 xnv;
    xnv.x = (v.x - mean) * rstd * gg.x + bb.x;
    xnv.y = (v.y - mean) * rstd * gg.y + bb.y;
    xnv.z = (v.z - mean) * rstd * gg.z + bb.z;
    xnv.w = (v.w - mean) * rstd * gg.w + bb.w;
    uint2 o; o.x = pack2bf(xnv.x, xnv.y); o.y = pack2bf(xnv.z, xnv.w);
    ((uint2*)(xn + (size_t)row * E_DIM))[t] = o;
    const float4 w1 = ((const float4*)wgw)[t];
    const float4 w2 = ((const float4*)wgf)[t];
    float dg = xnv.x * w1.x + xnv.y * w1.y + xnv.z * w1.z + xnv.w * w1.w;
    float df = xnv.x * w2.x + xnv.y * w2.y + xnv.z * w2.z + xnv.w * w2.w;
    block_reduce_2(dg, df, red, t);
    if (t == 0) {
        beta[row]  = sigmoidf_(dg + bgw[0]);
        decay[row] = sigmoidf_(df + bgf[0]);
    }
}

__global__ __launch_bounds__(256) void ln2_kernel(
    const float* __restrict__ y1, const float* __restrict__ g, const float* __restrict__ b,
    u16* __restrict__ h)
{
    __shared__ float red[8];
    const int row = blockIdx.x;
    const int t = threadIdx.x;
    const float4 v = ((const float4*)(y1 + (size_t)row * E_DIM))[t];
    float s  = v.x + v.y + v.z + v.w;
    float ss = v.x * v.x + v.y * v.y + v.z * v.z + v.w * v.w;
    block_reduce_2(s, ss, red, t);
    const float mean = s * (1.0f / E_DIM);
    const float var  = ss * (1.0f / E_DIM) - mean * mean;
    const float rstd = rsqrtf(var + 1e-5f);
    const float4 gg = ((const float4*)g)[t];
    const float4 bb = ((const float4*)b)[t];
    float4 xnv;
    xnv.x = (v.x - mean) * rstd * gg.x + bb.x;
    xnv.y = (v.y - mean) * rstd * gg.y + bb.y;
    xnv.z = (v.z - mean) * rstd * gg.z + bb.z;
    xnv.w = (v.w - mean) * rstd * gg.w + bb.w;
    uint2 o; o.x = pack2bf(xnv.x, xnv.y); o.y = pack2bf(xnv.z, xnv.w);
    ((uint2*)(h + (size_t)row * E_DIM))[t] = o;
}

// ---------------- k/q/v activation ----------------
__global__ __launch_bounds__(256) void kqv_act(float* __restrict__ kqv) {
    __shared__ float red[8];
    const int row = blockIdx.x;
    const int t = threadIdx.x;
    float* p = kqv + (size_t)row * 768;
    float kv = p[t], qv = p[256 + t], vv = p[512 + t];
    float sk = kv * kv, sq = qv * qv;
    block_reduce_2(sk, sq, red, t);
    float nk = fmaxf(sqrtf(sk), 1e-12f);
    float nq = fmaxf(sqrtf(sq), 1e-12f);
    p[t]       = kv / nk;
    p[256 + t] = qv / nq;
    p[512 + t] = tanhf(vv);
}

// ---------------- chunk prep ----------------
__global__ void chunk_prep(const float* __restrict__ beta, const float* __restrict__ decay,
                           float* __restrict__ P, float* __restrict__ ww) {
    int cb = blockIdx.x;
    int b = cb >> 5, c = cb & 31;
    int tb = b * S_DIM + c * CHUNK;
    int j = threadIdx.x;
    __shared__ float d[64], bt[64], Ps[65];
    d[j]  = decay[tb + j];
    bt[j] = beta[tb + j];
    __syncthreads();
    if (j == 0) {
        float p = 1.0f; Ps[0] = 1.0f;
        for (int i = 0; i < 64; i++) { p *= d[i]; Ps[i + 1] = p; }
    }
    __syncthreads();
    P[cb * 65 + j] = Ps[j];
    if (j == 0) P[cb * 65 + 64] = Ps[64];
    ww[cb * 64 + j] = bt[j] / Ps[j + 1];
}

// ---------------- per-chunk state increment ----------------
__global__ __launch_bounds__(256) void t_kernel(const float* __restrict__ kqv,
                                                const float* __restrict__ P,
                                                const float* __restrict__ ww,
                                                float* __restrict__ T) {
    int cb = blockIdx.y;
    int tile = blockIdx.x;
    int r0 = (tile >> 2) * 64, c0 = (tile & 3) * 64;
    int b = cb >> 5, c = cb & 31;
    int tb = b * S_DIM + c * CHUNK;
    float p64 = P[cb * 65 + 64];
    __shared__ float Vs[64][65], Ks[64][65];
    int t = threadIdx.x;
#pragma unroll
    for (int i = 0; i < 16; i++) {
        int idx = t + i * 256; int j = idx >> 6, col = idx & 63;
        float sc = ww[cb * 64 + j] * p64;
        Vs[j][col] = kqv[(size_t)(tb + j) * 768 + 512 + r0 + col] * sc;
        Ks[j][col] = kqv[(size_t)(tb + j) * 768 + 0   + c0 + col];
    }
    __syncthreads();
    int tr = t >> 4, tc = t & 15;
    float a[4][4] = {};
    for (int j = 0; j < 64; j++) {
        float vv[4], kk[4];
#pragma unroll
        for (int r = 0; r < 4; r++)  vv[r] = Vs[j][tr * 4 + r];
#pragma unroll
        for (int cc = 0; cc < 4; cc++) kk[cc] = Ks[j][tc * 4 + cc];
#pragma unroll
        for (int r = 0; r < 4; r++)
#pragma unroll
            for (int cc = 0; cc < 4; cc++) a[r][cc] += vv[r] * kk[cc];
    }
#pragma unroll
    for (int r = 0; r < 4; r++)
#pragma unroll
        for (int cc = 0; cc < 4; cc++)
            T[(size_t)cb * 65536 + (size_t)(r0 + tr * 4 + r) * 256 + (c0 + tc * 4 + cc)] = a[r][cc];
}

// ---------------- element-parallel chunk scan ----------------
__global__ void mem_scan(const float* __restrict__ mem0, const float* __restrict__ T,
                         const float* __restrict__ P, float* __restrict__ states,
                         float* __restrict__ memOut) {
    int gid = blockIdx.x * 256 + threadIdx.x;
    int b = gid >> 16; int e = gid & 65535;
    float s = mem0[gid];
    for (int c = 0; c < NCHUNK; c++) {
        int cb = b * NCHUNK + c;
        states[(size_t)cb * 65536 + e] = s;
        s = P[cb * 65 + 64] * s + T[(size_t)cb * 65536 + e];
    }
    memOut[gid] = s;
}

// ---------------- intra-chunk attention matrix ----------------
__global__ __launch_bounds__(256) void qk_attn(const float* __restrict__ kqv,
                                               const float* __restrict__ P,
                                               const float* __restrict__ ww,
                                               float* __restrict__ Abuf) {
    int cb = blockIdx.x;
    int b = cb >> 5, c = cb & 31;
    int tb = b * S_DIM + c * CHUNK;
    __shared__ float Qs[64][65], Ks[64][65];
    int t = threadIdx.x;
    int tr = t >> 4, tc = t & 15;
    float acc[4][4] = {};
    for (int kt = 0; kt < 4; kt++) {
        __syncthreads();
#pragma unroll
        for (int i = 0; i < 16; i++) {
            int idx = t + i * 256; int rr = idx >> 6, cc2 = idx & 63;
            Qs[rr][cc2] = kqv[(size_t)(tb + rr) * 768 + 256 + kt * 64 + cc2];
            Ks[rr][cc2] = kqv[(size_t)(tb + rr) * 768 + 0   + kt * 64 + cc2];
        }
        __syncthreads();
        for (int kk = 0; kk < 64; kk++) {
            float qq[4], kx[4];
#pragma unroll
            for (int r = 0; r < 4; r++)  qq[r] = Qs[tr * 4 + r][kk];
#pragma unroll
            for (int cc = 0; cc < 4; cc++) kx[cc] = Ks[tc * 4 + cc][kk];
#pragma unroll
            for (int r = 0; r < 4; r++)
#pragma unroll
                for (int cc = 0; cc < 4; cc++) acc[r][cc] += qq[r] * kx[cc];
        }
    }
#pragma unroll
    for (int r = 0; r < 4; r++) {
#pragma unroll
        for (int cc = 0; cc < 4; cc++) {
            int i = tr * 4 + r, j = tc * 4 + cc;
            float v = (j < i) ? acc[r][cc] * (P[cb * 65 + i] * ww[cb * 64 + j]) : 0.0f;
            Abuf[(size_t)cb * 4096 + i * 64 + j] = v;
        }
    }
}

// ---------------- readout ----------------
__global__ __launch_bounds__(256) void readout_k(const float* __restrict__ kqv,
                                                 const float* __restrict__ Abuf,
                                                 const float* __restrict__ states,
                                                 const float* __restrict__ P,
                                                 u16* __restrict__ ro) {
    int cb = blockIdx.y;
    int rt = blockIdx.x;
    int b = cb >> 5, c = cb & 31;
    int tb = b * S_DIM + c * CHUNK;
    int r0 = rt * 64;
    __shared__ float As[64][65], Vs[64][65], Qs[64][65], Ms[64][65];
    int t = threadIdx.x;
    int tr = t >> 4, tc = t & 15;
#pragma unroll
    for (int i = 0; i < 16; i++) {
        int idx = t + i * 256; int rr = idx >> 6, cc2 = idx & 63;
        As[rr][cc2] = Abuf[(size_t)cb * 4096 + rr * 64 + cc2];
        Vs[rr][cc2] = kqv[(size_t)(tb + rr) * 768 + 512 + r0 + cc2];
    }
    __syncthreads();
    float acc[4][4] = {};
    for (int j = 0; j < 64; j++) {
        float aa[4], vv[4];
#pragma unroll
        for (int r = 0; r < 4; r++)  aa[r] = As[tr * 4 + r][j];
#pragma unroll
        for (int cc = 0; cc < 4; cc++) vv[cc] = Vs[j][tc * 4 + cc];
#pragma unroll
        for (int r = 0; r < 4; r++)
#pragma unroll
            for (int cc = 0; cc < 4; cc++) acc[r][cc] += aa[r] * vv[cc];
    }
    float acc2[4][4] = {};
    for (int kt = 0; kt < 4; kt++) {
        __syncthreads();
#pragma unroll
        for (int i = 0; i < 16; i++) {
            int idx = t + i * 256; int rr = idx >> 6, cc2 = idx & 63;
            Qs[rr][cc2] = kqv[(size_t)(tb + rr) * 768 + 256 + kt * 64 + cc2];
            Ms[rr][cc2] = states[(size_t)cb * 65536 + (size_t)(r0 + rr) * 256 + kt * 64 + cc2];
        }
        __syncthreads();
        for (int kk = 0; kk < 64; kk++) {
            float qq[4], mm[4];
#pragma unroll
            for (int r = 0; r < 4; r++)  qq[r] = Qs[tr * 4 + r][kk];
#pragma unroll
            for (int cc = 0; cc < 4; cc++) mm[cc] = Ms[tc * 4 + cc][kk];
#pragma unroll
            for (int r = 0; r < 4; r++)
#pragma unroll
                for (int cc = 0; cc < 4; cc++) acc2[r][cc] += qq[r] * mm[cc];
        }
    }
#pragma unroll
    for (int r = 0; r < 4; r++) {
#pragma unroll
        for (int cc = 0; cc < 4; cc++) {
            int i = tr * 4 + r;
            float val = acc[r][cc] + P[cb * 65 + i] * acc2[r][cc];
            ro[(size_t)(tb + i) * 256 + r0 + tc * 4 + cc] = f2bf(val);
        }
    }
}

// ---------------- bf16 MFMA GEMM: C[M,N] = A[M,K] @ B[N,K]^T (+epilogue) ----------------
// BMx128 tile (BM=128: 4 waves as 2x2 of 64x64; BM=64: 2x2 of 32x64), BK=32,
// 16x16x32 MFMA. Double-buffered LDS + global_load_lds(16B), ONE barrier per
// K-iter (loads for k+1 fly during k's MFMA). XOR-swizzled LDS layout (sw_slot/
// sw_read) -> 2-way bank access on frag reads (free) instead of 8-way.
#define EPI_BIAS  0
#define EPI_RESID 1
#define EPI_GELU  2

template<int EPI, int BM>
__global__ __launch_bounds__(256) void gemm_bt(
    const u16* __restrict__ A, int lda,
    const u16* __restrict__ B, int ldb,
    const float* __restrict__ bias,
    const float* __restrict__ resid,
    float* __restrict__ outF, u16* __restrict__ outB,
    int ldc, int K)
{
    constexpr int MI = BM / 32;            // A-frags per wave (wave covers BM/2 rows)
    __shared__ u16 As[2][BM * 32];
    __shared__ u16 Bs[2][128 * 32];
    const int t = threadIdx.x;
    const int lane = t & 63;
    const int w = t >> 6;
    const int waveM = (w >> 1) * (BM / 2);
    const int waveN = (w & 1) * 64;
    const int m0 = blockIdx.y * BM;
    const int n0 = blockIdx.x * 128;

    // staging: slot idx -> row = idx>>2, swizzled col = sw_slot(idx).
    // note sw_slot(t+256) == sw_slot(t) since bit8 doesn't feed (idx>>3)&3... it does:
    // (t+256)>>3 = (t>>3)+32, &3 unchanged. So one col per thread.
    const int sr = t >> 2, scw = sw_slot(t);
    const u16* Ag0 = A + (size_t)(m0 + sr) * lda + scw;
    const u16* Ag1 = A + (size_t)(m0 + 64 + sr) * lda + scw;   // only used when BM==128
    const u16* Bg0 = B + (size_t)(n0 + sr) * ldb + scw;
    const u16* Bg1 = B + (size_t)(n0 + 64 + sr) * ldb + scw;

    floatx4 acc[MI][4] = {};

    const int kc = lane >> 4;              // k-chunk selector (0..3)
    const int rsel = lane & 15;
    const int NK = K >> 5;

    // prologue: stage tile 0 into buffer 0
    gload_lds16(Ag0, As[0] + t * 8);
    if (BM == 128) gload_lds16(Ag1, As[0] + (t + 256) * 8);
    gload_lds16(Bg0, Bs[0] + t * 8);
    gload_lds16(Bg1, Bs[0] + (t + 256) * 8);

    for (int kt = 0; kt < NK; kt++) {
        __syncthreads();                   // drains buf[kt&1] loads (vmcnt) + prev ds_reads (lgkm)
        const int cur = kt & 1;
        if (kt + 1 < NK) {
            const int kof = (kt + 1) * 32;
            gload_lds16(Ag0 + kof, As[cur ^ 1] + t * 8);
            if (BM == 128) gload_lds16(Ag1 + kof, As[cur ^ 1] + (t + 256) * 8);
            gload_lds16(Bg0 + kof, Bs[cur ^ 1] + t * 8);
            gload_lds16(Bg1 + kof, Bs[cur ^ 1] + (t + 256) * 8);
        }
        short8 af[MI], bfr[4];
#pragma unroll
        for (int i = 0; i < MI; i++)
            af[i] = *(const short8*)(As[cur] + sw_read(waveM + i * 16 + rsel, kc));
#pragma unroll
        for (int j = 0; j < 4; j++)
            bfr[j] = *(const short8*)(Bs[cur] + sw_read(waveN + j * 16 + rsel, kc));
#pragma unroll
        for (int i = 0; i < MI; i++)
#pragma unroll
            for (int j = 0; j < 4; j++)
                acc[i][j] = __builtin_amdgcn_mfma_f32_16x16x32_bf16(af[i], bfr[j], acc[i][j], 0, 0, 0);
    }

    const int rbase = (lane >> 4) * 4;
#pragma unroll
    for (int i = 0; i < MI; i++) {
#pragma unroll
        for (int j = 0; j < 4; j++) {
            const int col = n0 + waveN + j * 16 + rsel;
            const float bv = bias[col];
#pragma unroll
            for (int r = 0; r < 4; r++) {
                const int row = m0 + waveM + i * 16 + rbase + r;
                const size_t oidx = (size_t)row * ldc + col;
                float v = acc[i][j][r] + bv;
                if (EPI == EPI_BIAS) {
                    outF[oidx] = v;
                } else if (EPI == EPI_RESID) {
                    outF[oidx] = v + resid[oidx];
                } else {
                    float gl = 0.5f * v * (1.0f + erff(v * 0.70710678118654752f));
                    outB[oidx] = f2bf(gl);
                }
            }
        }
    }
}

// ---------------- launch ----------------
extern "C" void kernel_launch(void* const* d_in, const int* in_sizes, int n_in,
                              void* d_out, int out_size, void* d_ws, size_t ws_size,
                              hipStream_t stream) {
    const float* x     = (const float*)d_in[0];
    const float* mem0  = (const float*)d_in[1];
    const float* w_k   = (const float*)d_in[2];
    const float* b_k   = (const float*)d_in[3];
    const float* w_q   = (const float*)d_in[4];
    const float* b_q   = (const float*)d_in[5];
    const float* w_v   = (const float*)d_in[6];
    const float* b_v   = (const float*)d_in[7];
    const float* w_out = (const float*)d_in[8];
    const float* b_out = (const float*)d_in[9];
    const float* w_gw  = (const float*)d_in[10];
    const float* b_gw  = (const float*)d_in[11];
    const float* w_gf  = (const float*)d_in[12];
    const float* b_gf  = (const float*)d_in[13];
    const float* ln1g  = (const float*)d_in[14];
    const float* ln1b  = (const float*)d_in[15];
    const float* ln2g  = (const float*)d_in[16];
    const float* ln2b  = (const float*)d_in[17];
    const float* w_f1  = (const float*)d_in[18];
    const float* b_f1  = (const float*)d_in[19];
    const float* w_f2  = (const float*)d_in[20];
    const float* b_f2  = (const float*)d_in[21];

    char* ws = (char*)d_ws;
    u16*   wkqv  = (u16*)(ws + OFF_WKQV);
    u16*   wout  = (u16*)(ws + OFF_WOUT);
    u16*   wf1   = (u16*)(ws + OFF_WF1);
    u16*   wf2   = (u16*)(ws + OFF_WF2);
    float* bkqv  = (float*)(ws + OFF_BKQV);
    float* beta  = (float*)(ws + OFF_BETA);
    float* decay = (float*)(ws + OFF_DECAY);
    float* P     = (float*)(ws + OFF_P);
    float* ww    = (float*)(ws + OFF_WW);
    float* Abuf  = (float*)(ws + OFF_ABUF);
    u16*   xn    = (u16*)(ws + OFF_XN);
    float* kqv   = (float*)(ws + OFF_KQV);
    float* T     = (float*)(ws + OFF_T);
    float* states= (float*)(ws + OFF_STATES);
    u16*   ro    = (u16*)(ws + OFF_RO);
    u16*   h     = (u16*)(ws + OFF_H);
    float* y1    = (float*)(ws + OFF_Y1);
    u16*   g     = (u16*)(ws + OFF_G);

    float* out_x   = (float*)d_out;
    float* out_mem = out_x + (size_t)NTOK * E_DIM;

    // weight conversion (runs every call: inputs restored each launch)
    pack_kqv_w<<<768, 256, 0, stream>>>((const float4*)w_k, (const float4*)w_q,
                                        (const float4*)w_v, (uint2*)wkqv);
    f2bf4_kernel<<<256, 256, 0, stream>>>((const float4*)w_out, (uint2*)wout, 1024 * 256 / 4);
    f2bf4_kernel<<<4096, 256, 0, stream>>>((const float4*)w_f1, (uint2*)wf1, 4096 * 1024 / 4);
    f2bf4_kernel<<<4096, 256, 0, stream>>>((const float4*)w_f2, (uint2*)wf2, 1024 * 4096 / 4);
    pack_bias<<<3, 256, 0, stream>>>(b_k, b_q, b_v, bkqv);

    // LN1 + gate scalars
    ln1_gates<<<NTOK, 256, 0, stream>>>(x, ln1g, ln1b, w_gw, b_gw, w_gf, b_gf, xn, beta, decay);

    // k/q/v projections: [8192,768] = xn @ wkqv^T   (BM=64 for block count)
    gemm_bt<EPI_BIAS, 64><<<dim3(6, 128), 256, 0, stream>>>(xn, 1024, wkqv, 1024, bkqv, nullptr,
                                                            kqv, nullptr, 768, 1024);
    kqv_act<<<NTOK, 256, 0, stream>>>(kqv);

    // chunked linear-attention scan
    chunk_prep<<<NCB, 64, 0, stream>>>(beta, decay, P, ww);
    t_kernel<<<dim3(16, NCB), 256, 0, stream>>>(kqv, P, ww, T);
    mem_scan<<<1024, 256, 0, stream>>>(mem0, T, P, states, out_mem);
    qk_attn<<<NCB, 256, 0, stream>>>(kqv, P, ww, Abuf);
    readout_k<<<dim3(4, NCB), 256, 0, stream>>>(kqv, Abuf, states, P, ro);

    // mixer + residual (BM=64: K=256 is latency-thin, needs block count)
    gemm_bt<EPI_RESID, 64><<<dim3(8, 128), 256, 0, stream>>>(ro, 256, wout, 256, b_out, x,
                                                             y1, nullptr, 1024, 256);
    // LN2 + FFN
    ln2_kernel<<<NTOK, 256, 0, stream>>>(y1, ln2g, ln2b, h);
    // FFN1: the FLOP monster -> BM=128 (64x64/wave = 2x FLOP per LDS byte), 2048 blocks
    gemm_bt<EPI_GELU, 128><<<dim3(32, 64), 256, 0, stream>>>(h, 1024, wf1, 1024, b_f1, nullptr,
                                                             nullptr, g, 4096, 1024);
    gemm_bt<EPI_RESID, 64><<<dim3(8, 128), 256, 0, stream>>>(g, 4096, wf2, 4096, b_f2, y1,
                                                             out_x, nullptr, 1024, 4096);
}